// Round 9
// baseline (198.550 us; speedup 1.0000x reference)
//
#include <hip/hip_runtime.h>
#include <math.h>

#define B_ 4
#define C_ 32
#define D_ 16
#define H_ 128
#define W_ 128
#define HW_ (H_*W_)
#define SP_ (D_*HW_)

// padded s layout: [B][2][D][H][PW], col = w + 2, w in [-2, 129] reflected
#define PW_ 136
#define PPL_ (H_*PW_)          // plane stride
#define PCH_ (D_*PPL_)         // channel (mean/max) stride
#define NPLANES (B_*D_)        // 64 (b,d) planes

typedef float f32x4 __attribute__((ext_vector_type(4)));
typedef float f32x4u __attribute__((ext_vector_type(4), aligned(4)));

__device__ __forceinline__ int refl(int i, int n) {
    i = (i < 0) ? -i : i;
    i = (i >= n) ? (2*n - 2 - i) : i;
    return i;
}

__global__ void zero_cnt_kernel(int* __restrict__ cnt) {
    if (threadIdx.x < NPLANES) cnt[threadIdx.x] = 0;
}

// Pass 0: combined stencil Wc[ci][od][oh][ow] (2x7x7x5)
__global__ void prep_weights_kernel(const float* __restrict__ w1,
                                    const float* __restrict__ w2,
                                    const float* __restrict__ w3,
                                    const float* __restrict__ wf,
                                    float* __restrict__ Wc) {
    int t = blockIdx.x * blockDim.x + threadIdx.x;
    if (t >= 2*7*7*5) return;
    int ow = t % 5;
    int oh = (t / 5) % 7;
    int od = (t / 35) % 7;
    int ci = t / 245;
    float v = wf[0] * w1[((ci*7+od)*7+oh)*5+ow];
    if (od>=1 && od<=5 && oh>=1 && oh<=5 && ow>=1 && ow<=3)
        v = fmaf(wf[1], w2[((ci*5+(od-1))*5+(oh-1))*3+(ow-1)], v);
    if (od>=2 && od<=4 && oh>=2 && oh<=4 && ow==2)
        v = fmaf(wf[2], w3[(ci*3+(od-2))*3+(oh-2)], v);
    Wc[t] = v;
}

// Fused producer-consumer kernel. Grid = 1024 = 4 blocks/CU, all co-resident.
// bid < 512 : pool-role  — 1/8 of one (b,d) plane -> padded s; bump cnt[plane].
// bid >= 512: att-role   — wait for 8 reflected d-planes, then stencil+mult.
__global__ __launch_bounds__(256, 4) void fused_kernel(
        const float* __restrict__ x,
        float* __restrict__ s,
        const float* __restrict__ Wc,
        float* __restrict__ out,
        int* __restrict__ cnt) {
    int bid = blockIdx.x;
    int t = threadIdx.x;

    if (bid < 512) {
        // ---------------- pool role ----------------
        int p = bid >> 3;              // plane id = b*16 + d
        int b = p >> 4, d = p & 15;
        int h0b = (bid & 7) * 16;
        #pragma unroll
        for (int rep = 0; rep < 2; ++rep) {
            int it = t + rep*256;      // 512 items: 16 rows x 32 w-quads
            int w4 = (it & 31) * 4;
            int h  = h0b + (it >> 5);
            const float* xp = x + (b*C_*D_ + d)*HW_ + h*W_ + w4;
            f32x4 v = *(const f32x4*)xp;
            f32x4 sm = v, mx = v;
            #pragma unroll 8
            for (int c = 1; c < C_; ++c) {
                f32x4 u = *(const f32x4*)(xp + c*SP_);
                sm += u;
                mx.x=fmaxf(mx.x,u.x); mx.y=fmaxf(mx.y,u.y);
                mx.z=fmaxf(mx.z,u.z); mx.w=fmaxf(mx.w,u.w);
            }
            sm *= (1.0f/32.0f);
            float* rm = s + (b*2+0)*PCH_ + d*PPL_ + h*PW_;
            float* rM = s + (b*2+1)*PCH_ + d*PPL_ + h*PW_;
            *(f32x4u*)(rm + w4 + 2) = sm;
            *(f32x4u*)(rM + w4 + 2) = mx;
            if (w4 == 0) {              // cols 0,1 = w=-2,-1 -> refl 2,1
                rm[0] = sm.z; rm[1] = sm.y;
                rM[0] = mx.z; rM[1] = mx.y;
            } else if (w4 == 124) {     // cols 130,131 = w=128,129 -> refl 126,125
                rm[130] = sm.z; rm[131] = sm.y;
                rM[130] = mx.z; rM[131] = mx.y;
            }
        }
        __threadfence();               // make this thread's s-stores device-visible
        __syncthreads();               // all threads of block fenced
        if (t == 0) atomicAdd(&cnt[p], 1);
        return;
    }

    // ---------------- att role ----------------
    int abid = bid - 512;
    int ht = abid & 15;
    int dp = (abid >> 4) & 7;
    int b  = abid >> 7;
    int w0 = (t & 31) * 4;
    int h0 = ht * 8 + (t >> 5);
    int d0 = dp * 2;

    // input d-planes for outputs d0,d0+1: k=0..7 -> refl(d0+k-3)
    int drow[8];
    #pragma unroll
    for (int k = 0; k < 8; ++k) drow[k] = refl(d0 + k - 3, D_);

    // wait for the 8 producer planes of this batch
    if (t == 0) {
        #pragma unroll
        for (int k = 0; k < 8; ++k) {
            int p = b*16 + drow[k];
            while (atomicAdd(&cnt[p], 0) < 8)
                __builtin_amdgcn_s_sleep(2);
        }
    }
    __syncthreads();
    __threadfence();                   // acquire: see producers' s-stores

    float acc0[4] = {0.f, 0.f, 0.f, 0.f};
    float acc1[4] = {0.f, 0.f, 0.f, 0.f};

    for (int ci = 0; ci < 2; ++ci) {
        const float* sc = s + (b*2 + ci)*PCH_;
        const float* wcb_ci = Wc + ci*245;
        for (int oh = 0; oh < 7; ++oh) {
            const float* sh = sc + refl(h0 + oh - 3, H_)*PW_ + w0;
            const float* wcb = wcb_ci + oh*5;   // + od*35 + ow
            #pragma unroll
            for (int k = 0; k < 8; ++k) {
                const float* rp = sh + drow[k]*PPL_;
                const f32x4 L = *(const f32x4*)(rp);
                const f32x4 R = *(const f32x4*)(rp + 4);
                float v[8] = {L.x, L.y, L.z, L.w, R.x, R.y, R.z, R.w};
                if (k <= 6) {                    // output d0: od = k
                    const float* wp = wcb + k*35;
                    #pragma unroll
                    for (int ow = 0; ow < 5; ++ow) {
                        float wgt = wp[ow];
                        #pragma unroll
                        for (int wi = 0; wi < 4; ++wi)
                            acc0[wi] = fmaf(wgt, v[wi+ow], acc0[wi]);
                    }
                }
                if (k >= 1) {                    // output d0+1: od = k-1
                    const float* wp = wcb + (k-1)*35;
                    #pragma unroll
                    for (int ow = 0; ow < 5; ++ow) {
                        float wgt = wp[ow];
                        #pragma unroll
                        for (int wi = 0; wi < 4; ++wi)
                            acc1[wi] = fmaf(wgt, v[wi+ow], acc1[wi]);
                    }
                }
            }
        }
    }

    float sg0[4], sg1[4];
    #pragma unroll
    for (int wi = 0; wi < 4; ++wi) {
        sg0[wi] = 1.0f/(1.0f + __expf(-acc0[wi]));
        sg1[wi] = 1.0f/(1.0f + __expf(-acc1[wi]));
    }

    int obase = (b*C_*D_ + d0)*HW_ + h0*W_ + w0;
    #pragma unroll 8
    for (int c = 0; c < C_; ++c) {
        int i0 = obase + c*SP_;
        f32x4 xv0 = *(const f32x4*)(x + i0);
        f32x4 xv1 = *(const f32x4*)(x + i0 + HW_);
        f32x4 o0; o0.x=xv0.x*sg0[0]; o0.y=xv0.y*sg0[1]; o0.z=xv0.z*sg0[2]; o0.w=xv0.w*sg0[3];
        f32x4 o1; o1.x=xv1.x*sg1[0]; o1.y=xv1.y*sg1[1]; o1.z=xv1.z*sg1[2]; o1.w=xv1.w*sg1[3];
        __builtin_nontemporal_store(o0, (f32x4*)(out + i0));
        __builtin_nontemporal_store(o1, (f32x4*)(out + i0 + HW_));
    }
}

extern "C" void kernel_launch(void* const* d_in, const int* in_sizes, int n_in,
                              void* d_out, int out_size, void* d_ws, size_t ws_size,
                              hipStream_t stream) {
    const float* x  = (const float*)d_in[0];
    const float* w1 = (const float*)d_in[1];
    const float* w2 = (const float*)d_in[2];
    const float* w3 = (const float*)d_in[3];
    const float* wf = (const float*)d_in[4];
    float* out = (float*)d_out;
    float* Wc = (float*)d_ws;                         // 512 floats
    float* s  = (float*)d_ws + 512;                   // padded s, 8.9 MB
    int*   cnt = (int*)(s + (size_t)B_*2*PCH_);       // 64 plane counters

    zero_cnt_kernel<<<1, 64, 0, stream>>>(cnt);
    prep_weights_kernel<<<1, 512, 0, stream>>>(w1, w2, w3, wf, Wc);
    fused_kernel<<<1024, 256, 0, stream>>>(x, s, Wc, out, cnt);
}

// Round 10
// 84.746 us; speedup vs baseline: 2.3429x; 2.3429x over previous
//
#include <hip/hip_runtime.h>
#include <math.h>

#define B_ 4
#define C_ 32
#define D_ 16
#define H_ 128
#define W_ 128
#define HW_ (H_*W_)
#define SP_ (D_*HW_)

// padded s layout: [B][2][D][H][PW], col = w + 2, w in [-2, 129] reflected
#define PW_ 136
#define PPL_ (H_*PW_)          // plane stride
#define PCH_ (D_*PPL_)         // channel (mean/max) stride

typedef float f32x4 __attribute__((ext_vector_type(4)));
typedef float f32x4u __attribute__((ext_vector_type(4), aligned(4)));

__device__ __forceinline__ int refl(int i, int n) {
    i = (i < 0) ? -i : i;
    i = (i >= n) ? (2*n - 2 - i) : i;
    return i;
}

// Pass 0: combined stencil Wc[ci][od][oh][ow] (2x7x7x5)
__global__ void prep_weights_kernel(const float* __restrict__ w1,
                                    const float* __restrict__ w2,
                                    const float* __restrict__ w3,
                                    const float* __restrict__ wf,
                                    float* __restrict__ Wc) {
    int t = blockIdx.x * blockDim.x + threadIdx.x;
    if (t >= 2*7*7*5) return;
    int ow = t % 5;
    int oh = (t / 5) % 7;
    int od = (t / 35) % 7;
    int ci = t / 245;
    float v = wf[0] * w1[((ci*7+od)*7+oh)*5+ow];
    if (od>=1 && od<=5 && oh>=1 && oh<=5 && ow>=1 && ow<=3)
        v = fmaf(wf[1], w2[((ci*5+(od-1))*5+(oh-1))*3+(ow-1)], v);
    if (od>=2 && od<=4 && oh>=2 && oh<=4 && ow==2)
        v = fmaf(wf[2], w3[(ci*3+(od-2))*3+(oh-2)], v);
    Wc[t] = v;
}

// Pass 1: channel pool -> padded s. col = w+2; edge cols 0,1,130,131 hold
// the w-reflection so stencil reads need no edge fixup and stay aligned.
__global__ __launch_bounds__(256) void pool_kernel(const float* __restrict__ x,
                                                   float* __restrict__ s) {
    int t = blockIdx.x * blockDim.x + threadIdx.x;
    if (t >= B_*D_*H_*(W_/4)) return;
    int w4 = (t % (W_/4)) * 4;
    int rest = t / (W_/4);
    int h = rest % H_;
    int bd = rest / H_;
    int d = bd % D_;
    int b = bd / D_;
    const float* xp = x + (b*C_*D_ + d)*HW_ + h*W_ + w4;
    f32x4 v = *(const f32x4*)xp;
    f32x4 sm = v, mx = v;
    #pragma unroll 8
    for (int c = 1; c < C_; ++c) {
        f32x4 u = *(const f32x4*)(xp + c*SP_);
        sm += u;
        mx.x=fmaxf(mx.x,u.x); mx.y=fmaxf(mx.y,u.y); mx.z=fmaxf(mx.z,u.z); mx.w=fmaxf(mx.w,u.w);
    }
    sm *= (1.0f/32.0f);
    float* rm = s + (b*2+0)*PCH_ + d*PPL_ + h*PW_;
    float* rM = s + (b*2+1)*PCH_ + d*PPL_ + h*PW_;
    *(f32x4u*)(rm + w4 + 2) = sm;
    *(f32x4u*)(rM + w4 + 2) = mx;
    if (w4 == 0) {              // cols 0,1 = w=-2,-1 -> refl 2,1
        rm[0] = sm.z; rm[1] = sm.y;
        rM[0] = mx.z; rM[1] = mx.y;
    } else if (w4 == 124) {     // cols 130,131 = w=128,129 -> refl 126,125
        rm[130] = sm.z; rm[131] = sm.y;
        rM[130] = mx.z; rM[131] = mx.y;
    }
}

// Pass 2 (merged): 2x7x7x5 stencil on padded s + sigmoid + x-multiply.
// Thread tile: 2 d x 1 h x 4 w. Block 256 = 32 w-tiles x 8 h.
// Grid: B*(D/2)*(H/8) = 512 blocks. All stencil loads are aligned f4.
// R10: regular (cached) stores — LLC absorbs the 134 MB out burst and
// drains lazily; NT was forcing the synchronous HBM write path.
__global__ __launch_bounds__(256, 2) void spatial_att_kernel(
        const float* __restrict__ x,
        const float* __restrict__ s,
        const float* __restrict__ Wc,
        float* __restrict__ out) {
    int bid = blockIdx.x;
    int ht = bid & 15;
    int dp = (bid >> 4) & 7;
    int b  = bid >> 7;
    int t = threadIdx.x;
    int w0 = (t & 31) * 4;
    int h0 = ht * 8 + (t >> 5);
    int d0 = dp * 2;

    // input d-planes for outputs d0 and d0+1: k = 0..7 -> d0 + k - 3 (reflected)
    int drow[8];
    #pragma unroll
    for (int k = 0; k < 8; ++k) drow[k] = refl(d0 + k - 3, D_) * PPL_;

    float acc0[4] = {0.f, 0.f, 0.f, 0.f};
    float acc1[4] = {0.f, 0.f, 0.f, 0.f};

    for (int ci = 0; ci < 2; ++ci) {
        const float* sc = s + (b*2 + ci)*PCH_;
        const float* wcb_ci = Wc + ci*245;
        for (int oh = 0; oh < 7; ++oh) {
            const float* sh = sc + refl(h0 + oh - 3, H_)*PW_ + w0;
            const float* wcb = wcb_ci + oh*5;   // + od*35 + ow
            #pragma unroll
            for (int k = 0; k < 8; ++k) {
                const float* rp = sh + drow[k];
                const f32x4 L = *(const f32x4*)(rp);
                const f32x4 R = *(const f32x4*)(rp + 4);
                float v[8] = {L.x, L.y, L.z, L.w, R.x, R.y, R.z, R.w};
                // output d0: od index = k (valid k<=6)
                if (k <= 6) {
                    const float* wp = wcb + k*35;
                    #pragma unroll
                    for (int ow = 0; ow < 5; ++ow) {
                        float wgt = wp[ow];
                        #pragma unroll
                        for (int wi = 0; wi < 4; ++wi)
                            acc0[wi] = fmaf(wgt, v[wi+ow], acc0[wi]);
                    }
                }
                // output d0+1: od index = k-1 (valid k>=1)
                if (k >= 1) {
                    const float* wp = wcb + (k-1)*35;
                    #pragma unroll
                    for (int ow = 0; ow < 5; ++ow) {
                        float wgt = wp[ow];
                        #pragma unroll
                        for (int wi = 0; wi < 4; ++wi)
                            acc1[wi] = fmaf(wgt, v[wi+ow], acc1[wi]);
                    }
                }
            }
        }
    }

    float sg0[4], sg1[4];
    #pragma unroll
    for (int wi = 0; wi < 4; ++wi) {
        sg0[wi] = 1.0f/(1.0f + __expf(-acc0[wi]));
        sg1[wi] = 1.0f/(1.0f + __expf(-acc1[wi]));
    }

    int obase = (b*C_*D_ + d0)*HW_ + h0*W_ + w0;
    #pragma unroll 8
    for (int c = 0; c < C_; ++c) {
        int i0 = obase + c*SP_;
        f32x4 xv0 = *(const f32x4*)(x + i0);
        f32x4 xv1 = *(const f32x4*)(x + i0 + HW_);
        f32x4 o0; o0.x=xv0.x*sg0[0]; o0.y=xv0.y*sg0[1]; o0.z=xv0.z*sg0[2]; o0.w=xv0.w*sg0[3];
        f32x4 o1; o1.x=xv1.x*sg1[0]; o1.y=xv1.y*sg1[1]; o1.z=xv1.z*sg1[2]; o1.w=xv1.w*sg1[3];
        *(f32x4*)(out + i0) = o0;
        *(f32x4*)(out + i0 + HW_) = o1;
    }
}

extern "C" void kernel_launch(void* const* d_in, const int* in_sizes, int n_in,
                              void* d_out, int out_size, void* d_ws, size_t ws_size,
                              hipStream_t stream) {
    const float* x  = (const float*)d_in[0];
    const float* w1 = (const float*)d_in[1];
    const float* w2 = (const float*)d_in[2];
    const float* w3 = (const float*)d_in[3];
    const float* wf = (const float*)d_in[4];
    float* out = (float*)d_out;
    float* Wc = (float*)d_ws;            // 512 floats
    float* s  = (float*)d_ws + 512;      // padded [B][2][D][H][136] = 8.9 MB

    prep_weights_kernel<<<1, 512, 0, stream>>>(w1, w2, w3, wf, Wc);
    pool_kernel<<<(B_*D_*H_*(W_/4) + 255)/256, 256, 0, stream>>>(x, s);
    spatial_att_kernel<<<B_*(D_/2)*(H_/8), 256, 0, stream>>>(x, s, Wc, out);
}